// Round 3
// baseline (506.967 us; speedup 1.0000x reference)
//
#include <hip/hip_runtime.h>
#include <math.h>

// GRU-D, diagonal weights: independent scalar recurrence per (b,f) over T.
// R2: barrier-FREE producer/consumer pipeline. __syncthreads drains vmcnt(0),
// which caps bytes-in-flight at one burst (R1 lesson). Here loader waves
// free-run a 4-chunk-deep register pipeline (12 float4/thread outstanding,
// ~43KB/CU in flight) into a 4-slot LDS ring, synced with compute waves via
// LDS flags + ds atomics + lgkmcnt-only fences (vmcnt never drained).

#define TT 512
#define BB 256
#define FF 256
#define BF (BB * FF)
#define CH 4                 // steps per chunk
#define NCH (TT / CH)        // 128 chunks
#define DSLOTS 4             // LDS ring slots

__device__ __forceinline__ float fast_sigmoid(float x) {
    return __builtin_amdgcn_rcpf(1.0f + __expf(-x));
}
__device__ __forceinline__ float fast_tanh(float x) {
    return fmaf(-2.0f, __builtin_amdgcn_rcpf(1.0f + __expf(2.0f * x)), 1.0f);
}

__global__ __launch_bounds__(512) void grud_kernel(
    const float* __restrict__ X, const float* __restrict__ Mask,
    const float* __restrict__ Delta,
    const float* __restrict__ x_mean,
    const float* __restrict__ w_dg_x, const float* __restrict__ b_dg_x,
    const float* __restrict__ w_dg_h, const float* __restrict__ b_dg_h,
    const float* __restrict__ w_xz, const float* __restrict__ u_hz,
    const float* __restrict__ b_z,
    const float* __restrict__ w_xr, const float* __restrict__ u_hr,
    const float* __restrict__ b_r,
    const float* __restrict__ w_xh, const float* __restrict__ u_hh,
    const float* __restrict__ v_mh, const float* __restrict__ b_h,
    float* __restrict__ out)
{
    // ring[slot][arr][step][f] : 4*3*4*256*4B = 48 KiB
    __shared__ float ring[DSLOTS][3][CH][FF];
    __shared__ int produced[DSLOTS];
    __shared__ int consumed[DSLOTS];

    const int tid = threadIdx.x;
    const int blk = blockIdx.x;            // batch index b

    if (tid < DSLOTS) { produced[tid] = 0; consumed[tid] = 0; }
    __syncthreads();                        // once, before any vmem in flight

    if (tid >= 256) {
        // ---------------- loader waves (4) ----------------
        const int j   = tid - 256;          // 0..255
        const int stp = j >> 6;             // 0..3 (one step per wave)
        const int f4  = (j & 63) << 2;      // 0,4,...,252
        const size_t eoff = (size_t)blk * FF + (size_t)stp * BF + f4;
        const float* sX = X     + eoff;
        const float* sM = Mask  + eoff;
        const float* sD = Delta + eoff;
        const int lane0 = ((tid & 63) == 0);

        float4 R0[3], R1[3], R2[3], R3[3];

        auto issue = [&](int chunk, float4 (&R)[3]) {
            const size_t o = (size_t)chunk * (CH * BF);
            R[0] = *(const float4*)(sX + o);
            R[1] = *(const float4*)(sM + o);
            R[2] = *(const float4*)(sD + o);
        };
        auto process = [&](int k, float4 (&R)[3]) {
            const int s = k & (DSLOTS - 1);
            const int g = k >> 2;
            volatile int* cons = consumed + s;
            const int tgt = 4 * g;          // 4 compute waves per generation
            while (*cons < tgt) __builtin_amdgcn_s_sleep(1);
            asm volatile("" ::: "memory");
            *(float4*)&ring[s][0][stp][f4] = R[0];
            *(float4*)&ring[s][1][stp][f4] = R[1];
            *(float4*)&ring[s][2][stp][f4] = R[2];
            asm volatile("s_waitcnt lgkmcnt(0)" ::: "memory");
            if (lane0) atomicAdd(&produced[s], 1);
            if (k + 4 < NCH) issue(k + 4, R);
        };

        issue(0, R0); issue(1, R1); issue(2, R2); issue(3, R3);
        for (int kb = 0; kb < NCH; kb += 4) {
            process(kb + 0, R0);
            process(kb + 1, R1);
            process(kb + 2, R2);
            process(kb + 3, R3);
        }
    } else {
        // ---------------- compute waves (4) ----------------
        const int f = tid;
        const float xm  = x_mean[f];
        const float wdx = w_dg_x[f], bdx = b_dg_x[f];
        const float wdh = w_dg_h[f], bdh = b_dg_h[f];
        const float wxz = w_xz[f],   uhz = u_hz[f], bz = b_z[f];
        const float wxr = w_xr[f],   uhr = u_hr[f], br = b_r[f];
        const float wxh = w_xh[f],   uhh = u_hh[f];
        const float vmh = v_mh[f],   bh  = b_h[f];
        const int lane0 = ((tid & 63) == 0);

        float h = 0.0f;
        float* ob = out + (size_t)blk * (TT * FF) + f;

        for (int k = 0; k < NCH; ++k) {
            const int s = k & (DSLOTS - 1);
            const int g = k >> 2;
            volatile int* prod = produced + s;
            const int tgt = 4 * (g + 1);    // 4 loader waves per fill
            while (*prod < tgt) __builtin_amdgcn_s_sleep(1);
            asm volatile("" ::: "memory");

            float* op = ob + (size_t)(k * CH) * FF;
            #pragma unroll
            for (int st = 0; st < CH; ++st) {
                float x = ring[s][0][st][f];
                float m = ring[s][1][st][f];
                float d = ring[s][2][st][f];

                // off-chain (no dependence on h):
                float gx = __expf(-fmaxf(0.0f, fmaf(wdx, d, bdx)));
                float gh = __expf(-fmaxf(0.0f, fmaf(wdh, d, bdh)));
                float xv = fmaf(gx, x, (1.0f - gx) * xm);
                xv = fmaf(m, x, (1.0f - m) * xv);
                float az = fmaf(wxz, xv, bz);
                float ar = fmaf(wxr, xv, br);
                float ah = fmaf(wxh, xv, fmaf(vmh, m, bh));
                // on-chain:
                float u  = gh * h;
                float z  = fast_sigmoid(fmaf(uhz, u, az));
                float r  = fast_sigmoid(fmaf(uhr, u, ar));
                float ht = fast_tanh(fmaf(uhh, r * u, ah));
                h = fmaf(z, ht - u, u);      // (1-z)*u + z*ht
                op[st * FF] = h;
            }
            asm volatile("s_waitcnt lgkmcnt(0)" ::: "memory");
            if (lane0) atomicAdd(&consumed[s], 1);
        }

        out[(size_t)BB * TT * FF + (size_t)blk * FF + f] = h;
    }
}

extern "C" void kernel_launch(void* const* d_in, const int* in_sizes, int n_in,
                              void* d_out, int out_size, void* d_ws, size_t ws_size,
                              hipStream_t stream) {
    const float* X      = (const float*)d_in[0];
    const float* Mask   = (const float*)d_in[1];
    const float* Delta  = (const float*)d_in[2];
    const float* x_mean = (const float*)d_in[3];
    const float* w_dg_x = (const float*)d_in[4];
    const float* b_dg_x = (const float*)d_in[5];
    const float* w_dg_h = (const float*)d_in[6];
    const float* b_dg_h = (const float*)d_in[7];
    const float* w_xz   = (const float*)d_in[8];
    const float* u_hz   = (const float*)d_in[9];
    const float* b_z    = (const float*)d_in[10];
    const float* w_xr   = (const float*)d_in[11];
    const float* u_hr   = (const float*)d_in[12];
    const float* b_r    = (const float*)d_in[13];
    const float* w_xh   = (const float*)d_in[14];
    const float* u_hh   = (const float*)d_in[15];
    const float* v_mh   = (const float*)d_in[16];
    const float* b_h    = (const float*)d_in[17];
    float* out = (float*)d_out;

    grud_kernel<<<BB, 512, 0, stream>>>(
        X, Mask, Delta, x_mean, w_dg_x, b_dg_x, w_dg_h, b_dg_h,
        w_xz, u_hz, b_z, w_xr, u_hr, b_r, w_xh, u_hh, v_mh, b_h, out);
}